// Round 6
// baseline (1824.809 us; speedup 1.0000x reference)
//
#include <hip/hip_runtime.h>
#include <hip/hip_bf16.h>
#include <math.h>

// Problem constants
#define NNODE 17
#define HF    128      // GCN hidden
#define TT    128      // time steps
#define BB    256      // batch
#define LHID  256      // LSTM hidden
#define G4    1024     // 4*LHID
#define ZSTR  1032     // zbuf row stride (pad from 1024: kills 32-bank stride conflict)

typedef short short8 __attribute__((ext_vector_type(8)));
typedef float f32x4  __attribute__((ext_vector_type(4)));

// ws layout in floats
#define OFF_AHAT   0                         // 289 (pad 512)
#define OFF_WIT    512                       // 128*1024
#define OFF_BIAS   (OFF_WIT + 131072)        // 1024
#define OFF_WPK    (OFF_BIAS + 1024)         // 262144 ushort = 131072 floats (bf16-packed Whh)
#define OFF_POOLED (OFF_WPK + 131072)        // 32768*128
#define OFF_XW     (OFF_POOLED + 4194304)    // 32768*1024
#define OFF_FEAT   (OFF_XW + 33554432)       // 256*256
// total = 38,077,952 floats ~= 152 MB

__device__ inline unsigned int f2bf(float x) {   // fp32 -> bf16 bits, RNE
    unsigned int u = __float_as_uint(x);
    return (u + 0x7fffu + ((u >> 16) & 1u)) >> 16;
}

// ---------------- prep: A_hat from hard-coded edge list ----------------
__global__ __launch_bounds__(64) void prep_ahat_k(float* __restrict__ Ahat) {
    __shared__ float A[289];
    __shared__ float dinv[NNODE];
    const int t = threadIdx.x;
    for (int i = t; i < 289; i += 64) A[i] = 0.f;
    __syncthreads();
    if (t == 0) {
        const int es[17] = {0,0,1,2,1,5,7,6,8,5,5,6,11,11,13,12,14};
        const int et[17] = {5,6,2,4,3,7,9,8,10,6,11,12,12,13,15,14,16};
        for (int e = 0; e < 17; e++) A[et[e]*17 + es[e]] = 1.f;
        for (int n = 0; n < NNODE; n++) A[n*17 + n] += 1.f;
    }
    __syncthreads();
    if (t < NNODE) {
        float s = 0.f;
        for (int m = 0; m < NNODE; m++) s += A[t*17 + m];
        dinv[t] = rsqrtf(s);
    }
    __syncthreads();
    for (int i = t; i < 289; i += 64) {
        int n = i / 17, m = i % 17;
        Ahat[i] = dinv[n] * A[i] * dinv[m];
    }
}

// ---------------- prep: W_ih transpose + bias sum ----------------
__global__ __launch_bounds__(256) void prep_wt_k(
    const float* __restrict__ Wih,
    const float* __restrict__ bih, const float* __restrict__ bhh,
    float* __restrict__ WIT, float* __restrict__ bias_sum)
{
    const int k = blockIdx.x;       // 0..127
    const int g0 = threadIdx.x;
    for (int g = g0; g < G4; g += 256)
        WIT[(size_t)k*G4 + g] = Wih[(size_t)g*HF + k];
    if (k == 0)
        for (int g = g0; g < G4; g += 256)
            bias_sum[g] = bih[g] + bhh[g];
}

// ---------------- prep: pack Whh into bf16 MFMA B-fragment order ----------------
// B frag for mfma_f32_16x16x32_bf16: lane l supplies B[k][col], col = l&15,
// k = kc*32 + (l>>4)*8 + j (j=0..7). Packed layout:
// Wpk[ ((cg*8 + tt)*8 + kc)*512 + lane*8 + j ],  col = cg*128 + tt*16 + (lane&15)
__global__ __launch_bounds__(256) void prep_pack_k(
    const float* __restrict__ Whh, unsigned short* __restrict__ Wpk)
{
    const int tid = blockIdx.x * 256 + threadIdx.x;   // 0..32767
    const int lane = tid & 63;
    const int kc   = (tid >> 6) & 7;
    const int t    = (tid >> 9) & 7;
    const int w    = (tid >> 12) & 7;
    const int col  = w*128 + t*16 + (lane & 15);
    const int kb   = kc*32 + (lane >> 4)*8;
    const float4 v0 = *(const float4*)(Whh + (size_t)col*LHID + kb);
    const float4 v1 = *(const float4*)(Whh + (size_t)col*LHID + kb + 4);
    uint4 o;
    o.x = f2bf(v0.x) | (f2bf(v0.y) << 16);
    o.y = f2bf(v0.z) | (f2bf(v0.w) << 16);
    o.z = f2bf(v1.x) | (f2bf(v1.y) << 16);
    o.w = f2bf(v1.z) | (f2bf(v1.w) << 16);
    *(uint4*)(Wpk + (size_t)tid*8) = o;
}

// ---------------- GCN two layers + mean pool, one block per frame ----------------
__global__ __launch_bounds__(128) void gcn_pool_k(
    const float* __restrict__ kp, const float* __restrict__ W1,
    const float* __restrict__ b1, const float* __restrict__ W2,
    const float* __restrict__ b2, const float* __restrict__ Ahat,
    float* __restrict__ pooled)
{
    const int f = blockIdx.x;       // frame = b*T + t
    const int j = threadIdx.x;      // feature 0..127
    __shared__ float Ah[289];
    __shared__ float X[34];
    __shared__ float AhT[128][20];
    if (j < 34) X[j] = kp[(size_t)f*34 + j];
    for (int i = j; i < 289; i += 128) Ah[i] = Ahat[i];
    __syncthreads();
    float ax0[NNODE], ax1[NNODE];
    #pragma unroll
    for (int n = 0; n < NNODE; n++) {
        float s0 = 0.f, s1 = 0.f;
        #pragma unroll
        for (int m = 0; m < NNODE; m++) {
            float a = Ah[n*17 + m];
            s0 += a * X[2*m];
            s1 += a * X[2*m + 1];
        }
        ax0[n] = s0; ax1[n] = s1;
    }
    const float w10 = W1[j], w11 = W1[HF + j], bb1 = b1[j];
    float h1[NNODE];
    #pragma unroll
    for (int n = 0; n < NNODE; n++)
        h1[n] = fmaxf(fmaf(ax0[n], w10, fmaf(ax1[n], w11, bb1)), 0.f);
    float gcol[NNODE];
    #pragma unroll
    for (int n = 0; n < NNODE; n++) {
        float s = 0.f;
        #pragma unroll
        for (int m = 0; m < NNODE; m++) s += Ah[n*17 + m] * h1[m];
        gcol[n] = s;
    }
    #pragma unroll
    for (int n = 0; n < NNODE; n++) AhT[j][n] = gcol[n];
    __syncthreads();
    float acc[NNODE];
    #pragma unroll
    for (int n = 0; n < NNODE; n++) acc[n] = 0.f;
    for (int k = 0; k < HF; k++) {
        float w = W2[k*HF + j];
        #pragma unroll
        for (int n = 0; n < NNODE; n++) acc[n] = fmaf(AhT[k][n], w, acc[n]);
    }
    const float bb2 = b2[j];
    float s = 0.f;
    #pragma unroll
    for (int n = 0; n < NNODE; n++) s += fmaxf(acc[n] + bb2, 0.f);
    pooled[(size_t)f*HF + j] = s * (1.f/17.f);
}

// ---------------- xw = pooled @ W_ih^T + (b_ih+b_hh) ----------------
__global__ __launch_bounds__(256) void xw_gemm_k(
    const float* __restrict__ pooled, const float* __restrict__ WIT,
    const float* __restrict__ bias_sum, float* __restrict__ xw)
{
    const int row0 = blockIdx.x * 16;
    const int col  = blockIdx.y * 256 + threadIdx.x;
    __shared__ float P[16][HF];
    #pragma unroll
    for (int i = 0; i < 8; i++) {
        int e = threadIdx.x + i*256;
        P[e >> 7][e & 127] = pooled[(size_t)(row0 + (e >> 7))*HF + (e & 127)];
    }
    __syncthreads();
    float acc[16];
    #pragma unroll
    for (int r = 0; r < 16; r++) acc[r] = 0.f;
    for (int k = 0; k < HF; k++) {
        float w = WIT[(size_t)k*G4 + col];
        #pragma unroll
        for (int r = 0; r < 16; r++) acc[r] = fmaf(P[r][k], w, acc[r]);
    }
    float bs = bias_sum[col];
    #pragma unroll
    for (int r = 0; r < 16; r++)
        xw[(size_t)(row0 + r)*G4 + col] = acc[r] + bs;
}

// ---------------- MFMA LSTM v3: register-resident W_hh ----------------
// 32 blocks x 1024 threads (16 waves, 4/SIMD). Wave w owns 64 gate-cols:
// cg = w>>1 (128-col group), tt-half = w&1 (tiles (w&1)*4 .. +4), full K=256.
// W slice = 4tt x 8kc x short8 = 128 VGPRs, loaded ONCE before the t-loop
// (kills the 512 KB/step per-CU L2 stream that bounded rounds 4-5).
__global__ __launch_bounds__(1024, 4) void lstm_mfma_k(
    const float* __restrict__ xw, const unsigned short* __restrict__ Wpk,
    float* __restrict__ feat)
{
    const int b0  = blockIdx.x * 8;
    const int tid = threadIdx.x;
    const int w   = tid >> 6;
    const int l   = tid & 63;
    // epilogue mapping (round-5 verified): row = batch row, 2 cells/thread
    const int row = tid >> 7;          // 0..7
    const int u0  = (tid & 127) * 2;   // units u0, u0+1

    __shared__ float zbuf[8][ZSTR];                // 33 KB
    __shared__ unsigned short hpack[8][64][8];     // 8 KB, A-frag order

    // zero hpack (A rows 8..15 of the padded M stay zero forever)
    if (tid < 512) ((uint4*)hpack)[tid] = make_uint4(0u, 0u, 0u, 0u);

    // preload W slice into registers: global tt = (w&1)*4 + tt_local
    const unsigned short* wb = Wpk + (size_t)(w >> 1)*32768 + (size_t)(w & 1)*16384 + (size_t)l*8;
    short8 wreg[4][8];
    #pragma unroll
    for (int tt = 0; tt < 4; ++tt)
        #pragma unroll
        for (int kc = 0; kc < 8; ++kc)
            wreg[tt][kc] = *(const short8*)(wb + tt*4096 + kc*512);

    float c0 = 0.f, c1 = 0.f;
    float hm0 = -1e30f, hm1 = -1e30f;
    const float* xb = xw + ((size_t)(b0 + row)*TT)*G4 + u0;
    const int zr  = (l >> 4) * 4;                  // valid for l<32 (C rows 0..7)
    const int zc0 = (w >> 1)*128 + (w & 1)*64 + (l & 15);
    __syncthreads();

    for (int t = 0; t < TT; ++t) {
        // prefetch xg for this step's epilogue (hidden under MFMA phase)
        float2 xg[4];
        #pragma unroll
        for (int g = 0; g < 4; ++g)
            xg[g] = *(const float2*)(xb + (size_t)t*G4 + g*256);

        // A fragments (written by prev-step epilogue), full K: kc 0..7
        short8 a[8];
        #pragma unroll
        for (int kc = 0; kc < 8; ++kc)
            a[kc] = *(const short8*)&hpack[kc][l][0];

        // MFMA phase: 4 col-tiles of 16, W from registers (no memory traffic)
        #pragma unroll
        for (int tt = 0; tt < 4; ++tt) {
            f32x4 acc = {0.f, 0.f, 0.f, 0.f};
            #pragma unroll
            for (int kc = 0; kc < 8; ++kc)
                acc = __builtin_amdgcn_mfma_f32_16x16x32_bf16(a[kc], wreg[tt][kc], acc, 0, 0, 0);
            // C/D layout: col = lane&15, row = (lane>>4)*4 + reg [m89-verified]
            if (l < 32) {
                #pragma unroll
                for (int r = 0; r < 4; ++r)
                    zbuf[zr + r][tt*16 + zc0] = acc[r];
            }
        }
        __syncthreads();

        // epilogue: 2 cells per thread (row, u0/u0+1), gates fp32
        float2 zi = *(const float2*)&zbuf[row][0*256 + u0];
        float2 zf = *(const float2*)&zbuf[row][1*256 + u0];
        float2 zg = *(const float2*)&zbuf[row][2*256 + u0];
        float2 zo = *(const float2*)&zbuf[row][3*256 + u0];
        float hval[2];
        #pragma unroll
        for (int q = 0; q < 2; ++q) {
            float vi = ((const float*)&zi)[q] + ((const float*)&xg[0])[q];
            float vf = ((const float*)&zf)[q] + ((const float*)&xg[1])[q];
            float vg = ((const float*)&zg)[q] + ((const float*)&xg[2])[q];
            float vo = ((const float*)&zo)[q] + ((const float*)&xg[3])[q];
            float ii = __builtin_amdgcn_rcpf(1.f + __expf(-vi));
            float ff = __builtin_amdgcn_rcpf(1.f + __expf(-vf));
            float gg = 1.f - 2.f * __builtin_amdgcn_rcpf(__expf(2.f*vg) + 1.f);
            float oo = 1.f / (1.f + __expf(-vo));
            float cc = (q == 0) ? c0 : c1;
            float cn = fmaf(ff, cc, ii * gg);
            if (q == 0) c0 = cn; else c1 = cn;
            float th = 1.f - 2.f * __builtin_amdgcn_rcpf(__expf(2.f*cn) + 1.f);
            float hh = oo * th;
            if (q == 0) hm0 = fmaxf(hm0, hh); else hm1 = fmaxf(hm1, hh);
            hval[q] = hh;
        }
        // repack h -> bf16 A-frag layout: kc = u>>5, sub = ((u>>3)&3)*16 + row, j = u&7
        unsigned int hp = f2bf(hval[0]) | (f2bf(hval[1]) << 16);
        *(unsigned int*)&hpack[u0 >> 5][((u0 >> 3) & 3)*16 + row][u0 & 7] = hp;
        __syncthreads();
    }
    *(float2*)(feat + (size_t)(b0 + row)*LHID + u0) = make_float2(hm0, hm1);
}

// ---------------- final FC + sigmoid ----------------
__global__ __launch_bounds__(64) void final_k(
    const float* __restrict__ feat, const float* __restrict__ Wfc,
    const float* __restrict__ bfc, float* __restrict__ out)
{
    const int b = blockIdx.x * 64 + threadIdx.x;
    float s = bfc[0];
    for (int u = 0; u < LHID; u++)
        s = fmaf(feat[(size_t)b*LHID + u], Wfc[u], s);
    out[b] = 1.f / (1.f + __expf(-s));
}

extern "C" void kernel_launch(void* const* d_in, const int* in_sizes, int n_in,
                              void* d_out, int out_size, void* d_ws, size_t ws_size,
                              hipStream_t stream) {
    const float* kp  = (const float*)d_in[0];
    const float* W1  = (const float*)d_in[1];
    const float* b1  = (const float*)d_in[2];
    const float* W2  = (const float*)d_in[3];
    const float* b2  = (const float*)d_in[4];
    const float* Wih = (const float*)d_in[5];
    const float* Whh = (const float*)d_in[6];
    const float* bih = (const float*)d_in[7];
    const float* bhh = (const float*)d_in[8];
    const float* Wfc = (const float*)d_in[9];
    const float* bfc = (const float*)d_in[10];

    float* ws     = (float*)d_ws;
    float* Ahat   = ws + OFF_AHAT;
    float* WIT    = ws + OFF_WIT;
    float* bias   = ws + OFF_BIAS;
    unsigned short* Wpk = (unsigned short*)(ws + OFF_WPK);
    float* pooled = ws + OFF_POOLED;
    float* xw     = ws + OFF_XW;
    float* feat   = ws + OFF_FEAT;
    float* out    = (float*)d_out;

    hipLaunchKernelGGL(prep_ahat_k, dim3(1), dim3(64), 0, stream, Ahat);
    hipLaunchKernelGGL(prep_wt_k, dim3(128), dim3(256), 0, stream,
                       Wih, bih, bhh, WIT, bias);
    hipLaunchKernelGGL(prep_pack_k, dim3(128), dim3(256), 0, stream, Whh, Wpk);
    hipLaunchKernelGGL(gcn_pool_k, dim3(BB*TT), dim3(128), 0, stream,
                       kp, W1, b1, W2, b2, Ahat, pooled);
    hipLaunchKernelGGL(xw_gemm_k, dim3(BB*TT/16, 4), dim3(256), 0, stream,
                       pooled, WIT, bias, xw);
    hipLaunchKernelGGL(lstm_mfma_k, dim3(BB/8), dim3(1024), 0, stream, xw, Wpk, feat);
    hipLaunchKernelGGL(final_k, dim3(4), dim3(64), 0, stream, feat, Wfc, bfc, out);
}

// Round 10
// 1596.576 us; speedup vs baseline: 1.1430x; 1.1430x over previous
//
#include <hip/hip_runtime.h>
#include <hip/hip_bf16.h>
#include <math.h>

// Problem constants
#define NNODE 17
#define HF    128      // GCN hidden
#define TT    128      // time steps
#define BB    256      // batch
#define LHID  256      // LSTM hidden
#define G4    1024     // 4*LHID

typedef short short8 __attribute__((ext_vector_type(8)));
typedef float f32x4  __attribute__((ext_vector_type(4)));

// ws layout in floats
#define OFF_AHAT   0                         // 289 (pad 512)
#define OFF_WIT    512                       // 128*1024
#define OFF_BIAS   (OFF_WIT + 131072)        // 1024
#define OFF_WPK    (OFF_BIAS + 1024)         // 262144 ushort = 131072 floats (bf16-packed Whh)
#define OFF_POOLED (OFF_WPK + 131072)        // 32768*128
#define OFF_XW     (OFF_POOLED + 4194304)    // 32768*1024
#define OFF_FEAT   (OFF_XW + 33554432)       // 256*256
// total = 38,077,952 floats ~= 152 MB

__device__ inline unsigned int f2bf(float x) {   // fp32 -> bf16 bits, RNE
    unsigned int u = __float_as_uint(x);
    return (u + 0x7fffu + ((u >> 16) & 1u)) >> 16;
}

// ---------------- prep: A_hat from hard-coded edge list ----------------
__global__ __launch_bounds__(64) void prep_ahat_k(float* __restrict__ Ahat) {
    __shared__ float A[289];
    __shared__ float dinv[NNODE];
    const int t = threadIdx.x;
    for (int i = t; i < 289; i += 64) A[i] = 0.f;
    __syncthreads();
    if (t == 0) {
        const int es[17] = {0,0,1,2,1,5,7,6,8,5,5,6,11,11,13,12,14};
        const int et[17] = {5,6,2,4,3,7,9,8,10,6,11,12,12,13,15,14,16};
        for (int e = 0; e < 17; e++) A[et[e]*17 + es[e]] = 1.f;
        for (int n = 0; n < NNODE; n++) A[n*17 + n] += 1.f;
    }
    __syncthreads();
    if (t < NNODE) {
        float s = 0.f;
        for (int m = 0; m < NNODE; m++) s += A[t*17 + m];
        dinv[t] = rsqrtf(s);
    }
    __syncthreads();
    for (int i = t; i < 289; i += 64) {
        int n = i / 17, m = i % 17;
        Ahat[i] = dinv[n] * A[i] * dinv[m];
    }
}

// ---------------- prep: W_ih transpose + bias sum ----------------
__global__ __launch_bounds__(256) void prep_wt_k(
    const float* __restrict__ Wih,
    const float* __restrict__ bih, const float* __restrict__ bhh,
    float* __restrict__ WIT, float* __restrict__ bias_sum)
{
    const int k = blockIdx.x;       // 0..127
    const int g0 = threadIdx.x;
    for (int g = g0; g < G4; g += 256)
        WIT[(size_t)k*G4 + g] = Wih[(size_t)g*HF + k];
    if (k == 0)
        for (int g = g0; g < G4; g += 256)
            bias_sum[g] = bih[g] + bhh[g];
}

// ---------------- prep: pack Whh into bf16 MFMA B-fragment order ----------------
// B frag for mfma_f32_16x16x32_bf16: lane l supplies B[k][col], col = l&15,
// k = kc*32 + (l>>4)*8 + j (j=0..7). Packed layout:
// Wpk[ ((cg*8 + tt)*8 + kc)*512 + lane*8 + j ],  col = cg*128 + tt*16 + (lane&15)
__global__ __launch_bounds__(256) void prep_pack_k(
    const float* __restrict__ Whh, unsigned short* __restrict__ Wpk)
{
    const int tid = blockIdx.x * 256 + threadIdx.x;   // 0..32767
    const int lane = tid & 63;
    const int kc   = (tid >> 6) & 7;
    const int t    = (tid >> 9) & 7;
    const int w    = (tid >> 12) & 7;
    const int col  = w*128 + t*16 + (lane & 15);
    const int kb   = kc*32 + (lane >> 4)*8;
    const float4 v0 = *(const float4*)(Whh + (size_t)col*LHID + kb);
    const float4 v1 = *(const float4*)(Whh + (size_t)col*LHID + kb + 4);
    uint4 o;
    o.x = f2bf(v0.x) | (f2bf(v0.y) << 16);
    o.y = f2bf(v0.z) | (f2bf(v0.w) << 16);
    o.z = f2bf(v1.x) | (f2bf(v1.y) << 16);
    o.w = f2bf(v1.z) | (f2bf(v1.w) << 16);
    *(uint4*)(Wpk + (size_t)tid*8) = o;
}

// ---------------- GCN two layers + mean pool, one block per frame ----------------
__global__ __launch_bounds__(128) void gcn_pool_k(
    const float* __restrict__ kp, const float* __restrict__ W1,
    const float* __restrict__ b1, const float* __restrict__ W2,
    const float* __restrict__ b2, const float* __restrict__ Ahat,
    float* __restrict__ pooled)
{
    const int f = blockIdx.x;       // frame = b*T + t
    const int j = threadIdx.x;      // feature 0..127
    __shared__ float Ah[289];
    __shared__ float X[34];
    __shared__ float AhT[128][20];
    if (j < 34) X[j] = kp[(size_t)f*34 + j];
    for (int i = j; i < 289; i += 128) Ah[i] = Ahat[i];
    __syncthreads();
    float ax0[NNODE], ax1[NNODE];
    #pragma unroll
    for (int n = 0; n < NNODE; n++) {
        float s0 = 0.f, s1 = 0.f;
        #pragma unroll
        for (int m = 0; m < NNODE; m++) {
            float a = Ah[n*17 + m];
            s0 += a * X[2*m];
            s1 += a * X[2*m + 1];
        }
        ax0[n] = s0; ax1[n] = s1;
    }
    const float w10 = W1[j], w11 = W1[HF + j], bb1 = b1[j];
    float h1[NNODE];
    #pragma unroll
    for (int n = 0; n < NNODE; n++)
        h1[n] = fmaxf(fmaf(ax0[n], w10, fmaf(ax1[n], w11, bb1)), 0.f);
    float gcol[NNODE];
    #pragma unroll
    for (int n = 0; n < NNODE; n++) {
        float s = 0.f;
        #pragma unroll
        for (int m = 0; m < NNODE; m++) s += Ah[n*17 + m] * h1[m];
        gcol[n] = s;
    }
    #pragma unroll
    for (int n = 0; n < NNODE; n++) AhT[j][n] = gcol[n];
    __syncthreads();
    float acc[NNODE];
    #pragma unroll
    for (int n = 0; n < NNODE; n++) acc[n] = 0.f;
    for (int k = 0; k < HF; k++) {
        float w = W2[k*HF + j];
        #pragma unroll
        for (int n = 0; n < NNODE; n++) acc[n] = fmaf(AhT[k][n], w, acc[n]);
    }
    const float bb2 = b2[j];
    float s = 0.f;
    #pragma unroll
    for (int n = 0; n < NNODE; n++) s += fmaxf(acc[n] + bb2, 0.f);
    pooled[(size_t)f*HF + j] = s * (1.f/17.f);
}

// ---------------- xw = pooled @ W_ih^T + (b_ih+b_hh) ----------------
__global__ __launch_bounds__(256) void xw_gemm_k(
    const float* __restrict__ pooled, const float* __restrict__ WIT,
    const float* __restrict__ bias_sum, float* __restrict__ xw)
{
    const int row0 = blockIdx.x * 16;
    const int col  = blockIdx.y * 256 + threadIdx.x;
    __shared__ float P[16][HF];
    #pragma unroll
    for (int i = 0; i < 8; i++) {
        int e = threadIdx.x + i*256;
        P[e >> 7][e & 127] = pooled[(size_t)(row0 + (e >> 7))*HF + (e & 127)];
    }
    __syncthreads();
    float acc[16];
    #pragma unroll
    for (int r = 0; r < 16; r++) acc[r] = 0.f;
    for (int k = 0; k < HF; k++) {
        float w = WIT[(size_t)k*G4 + col];
        #pragma unroll
        for (int r = 0; r < 16; r++) acc[r] = fmaf(P[r][k], w, acc[r]);
    }
    float bs = bias_sum[col];
    #pragma unroll
    for (int r = 0; r < 16; r++)
        xw[(size_t)(row0 + r)*G4 + col] = acc[r] + bs;
}

// ---------------- MFMA LSTM v4: register-resident W_hh (asm-pinned) ----------------
// Round-4 structure (verified, 772 us): 32 blocks x 512 threads (8 waves), wave w
// owns gate cols [128w,128w+128), full K=256. W slice = 8tt x 8kc x short8 =
// 256 VGPRs, loaded ONCE and pinned via opaque asm so the compiler can neither
// rematerialize the loads in-loop nor treat them as respillable cheap values.
// This removes the 512 KB/step/CU L2 stream that roofline-bound rounds 4-6
// (~33 B/cyc/CU => ~6.6 us/step measured).
__global__ __launch_bounds__(512, 2) void lstm_mfma_k(
    const float* __restrict__ xw, const unsigned short* __restrict__ Wpk,
    float* __restrict__ feat)
{
    const int b0  = blockIdx.x * 8;
    const int tid = threadIdx.x;
    const int w   = tid >> 6;          // wave id = col-group AND epilogue row
    const int l   = tid & 63;
    const int eu0 = l << 2;            // epilogue unit base (4 units/thread)

    __shared__ float zbuf[8][G4];                 // 32 KB
    __shared__ unsigned short hpack[8][64][8];    // 8 KB, A-frag order

    // zero h (t=0 state); A rows 8..15 of the padded M stay zero forever
    ((uint4*)hpack)[tid] = make_uint4(0u, 0u, 0u, 0u);

    // ---- one-time W preload into registers, pinned ----
    const unsigned short* wb = Wpk + (size_t)w*32768 + (size_t)l*8;
    short8 wreg[8][8];
    #pragma unroll
    for (int tt = 0; tt < 8; ++tt) {
        #pragma unroll
        for (int kc = 0; kc < 8; ++kc) {
            wreg[tt][kc] = *(const short8*)(wb + tt*4096 + kc*512);
            asm volatile("" : "+v"(wreg[tt][kc]));   // opaque: kill remat, keep resident
        }
    }

    float c[4]  = {0.f, 0.f, 0.f, 0.f};
    float hm[4] = {-1e30f, -1e30f, -1e30f, -1e30f};
    const float* xwrow = xw + ((size_t)(b0 + w)*TT)*G4 + eu0;
    const int zr = (l >> 4) * 4;       // valid for l<32 (C rows 0..7)
    const int zc = w*128 + (l & 15);

    // prologue xg for t=0 (drains at the syncthreads below)
    float4 xg[4];
    #pragma unroll
    for (int g = 0; g < 4; ++g)
        xg[g] = *(const float4*)(xwrow + g*256);
    __syncthreads();

    for (int t = 0; t < TT; ++t) {
        // A fragments (written by prev-step epilogue)
        short8 a[8];
        #pragma unroll
        for (int kc = 0; kc < 8; ++kc)
            a[kc] = *(const short8*)&hpack[kc][l][0];

        // MFMA phase: 8 col-tiles of 16, W from registers (no memory traffic)
        #pragma unroll
        for (int tt = 0; tt < 8; ++tt) {
            f32x4 acc = {0.f, 0.f, 0.f, 0.f};
            #pragma unroll
            for (int kc = 0; kc < 8; ++kc)
                acc = __builtin_amdgcn_mfma_f32_16x16x32_bf16(a[kc], wreg[tt][kc], acc, 0, 0, 0);
            // C/D layout: col = lane&15, row = (lane>>4)*4 + reg [m89-verified]
            if (l < 32) {
                #pragma unroll
                for (int r = 0; r < 4; ++r)
                    zbuf[zr + r][tt*16 + zc] = acc[r];
            }
        }
        __syncthreads();

        // T14-style: issue next step's xg now; its vmcnt-drain lands on barrier 2
        float4 xgn[4];
        if (t + 1 < TT) {
            #pragma unroll
            for (int g = 0; g < 4; ++g)
                xgn[g] = *(const float4*)(xwrow + (size_t)(t+1)*G4 + g*256);
        }

        // epilogue (round-4 verified): 4 cells per thread (row = w, units eu0..eu0+3)
        float4 zi = *(const float4*)&zbuf[w][0*256 + eu0];
        float4 zf = *(const float4*)&zbuf[w][1*256 + eu0];
        float4 zg = *(const float4*)&zbuf[w][2*256 + eu0];
        float4 zo = *(const float4*)&zbuf[w][3*256 + eu0];
        float hval[4];
        #pragma unroll
        for (int q = 0; q < 4; ++q) {
            float vi = ((const float*)&zi)[q] + ((const float*)&xg[0])[q];
            float vf = ((const float*)&zf)[q] + ((const float*)&xg[1])[q];
            float vg = ((const float*)&zg)[q] + ((const float*)&xg[2])[q];
            float vo = ((const float*)&zo)[q] + ((const float*)&xg[3])[q];
            float ii = __builtin_amdgcn_rcpf(1.f + __expf(-vi));
            float ff = __builtin_amdgcn_rcpf(1.f + __expf(-vf));
            float gg = 1.f - 2.f * __builtin_amdgcn_rcpf(__expf(2.f*vg) + 1.f);
            float oo = 1.f / (1.f + __expf(-vo));
            float cn = fmaf(ff, c[q], ii * gg);
            c[q] = cn;
            float th = 1.f - 2.f * __builtin_amdgcn_rcpf(__expf(2.f*cn) + 1.f);
            float hh = oo * th;
            hm[q] = fmaxf(hm[q], hh);
            hval[q] = hh;
        }
        // repack h -> bf16 A-frag layout: kc = u>>5, sub = ((u>>3)&3)*16 + row, j = u&7
        unsigned int p01 = f2bf(hval[0]) | (f2bf(hval[1]) << 16);
        unsigned int p23 = f2bf(hval[2]) | (f2bf(hval[3]) << 16);
        *(uint2*)&hpack[eu0 >> 5][((eu0 >> 3) & 3)*16 + w][eu0 & 7] = make_uint2(p01, p23);
        __syncthreads();

        #pragma unroll
        for (int g = 0; g < 4; ++g) xg[g] = xgn[g];
    }
    *(float4*)(feat + (size_t)(b0 + w)*LHID + eu0) = make_float4(hm[0], hm[1], hm[2], hm[3]);
}

// ---------------- final FC + sigmoid ----------------
__global__ __launch_bounds__(64) void final_k(
    const float* __restrict__ feat, const float* __restrict__ Wfc,
    const float* __restrict__ bfc, float* __restrict__ out)
{
    const int b = blockIdx.x * 64 + threadIdx.x;
    float s = bfc[0];
    for (int u = 0; u < LHID; u++)
        s = fmaf(feat[(size_t)b*LHID + u], Wfc[u], s);
    out[b] = 1.f / (1.f + __expf(-s));
}

extern "C" void kernel_launch(void* const* d_in, const int* in_sizes, int n_in,
                              void* d_out, int out_size, void* d_ws, size_t ws_size,
                              hipStream_t stream) {
    const float* kp  = (const float*)d_in[0];
    const float* W1  = (const float*)d_in[1];
    const float* b1  = (const float*)d_in[2];
    const float* W2  = (const float*)d_in[3];
    const float* b2  = (const float*)d_in[4];
    const float* Wih = (const float*)d_in[5];
    const float* Whh = (const float*)d_in[6];
    const float* bih = (const float*)d_in[7];
    const float* bhh = (const float*)d_in[8];
    const float* Wfc = (const float*)d_in[9];
    const float* bfc = (const float*)d_in[10];

    float* ws     = (float*)d_ws;
    float* Ahat   = ws + OFF_AHAT;
    float* WIT    = ws + OFF_WIT;
    float* bias   = ws + OFF_BIAS;
    unsigned short* Wpk = (unsigned short*)(ws + OFF_WPK);
    float* pooled = ws + OFF_POOLED;
    float* xw     = ws + OFF_XW;
    float* feat   = ws + OFF_FEAT;
    float* out    = (float*)d_out;

    hipLaunchKernelGGL(prep_ahat_k, dim3(1), dim3(64), 0, stream, Ahat);
    hipLaunchKernelGGL(prep_wt_k, dim3(128), dim3(256), 0, stream,
                       Wih, bih, bhh, WIT, bias);
    hipLaunchKernelGGL(prep_pack_k, dim3(128), dim3(256), 0, stream, Whh, Wpk);
    hipLaunchKernelGGL(gcn_pool_k, dim3(BB*TT), dim3(128), 0, stream,
                       kp, W1, b1, W2, b2, Ahat, pooled);
    hipLaunchKernelGGL(xw_gemm_k, dim3(BB*TT/16, 4), dim3(256), 0, stream,
                       pooled, WIT, bias, xw);
    hipLaunchKernelGGL(lstm_mfma_k, dim3(BB/8), dim3(512), 0, stream, xw, Wpk, feat);
    hipLaunchKernelGGL(final_k, dim3(4), dim3(64), 0, stream, feat, Wfc, bfc, out);
}